// Round 7
// baseline (830.931 us; speedup 1.0000x reference)
//
#include <hip/hip_runtime.h>
#include <hip/hip_bf16.h>
#include <cstdint>
#include <cstddef>

// QRNN encoder, 3 layers. T=512 B=64 E=300 H=800.
// Chunked pipeline (4 chunks of T_C=128): per chunk, per layer:
//   bf16 MFMA GEMM (BK=64, XOR-swizzled LDS staging (0 bank conflicts),
//   XCD-aware block swizzle, 4 blocks/CU, fused fp32->bf16 A-staging for
//   layer 0, raw bf16 gates out, 2-barrier LDS-transpose epilogue)
//   -> segment-parallel fo-pool scan (z,f column-interleaved; bias+activation
//   fp32 in scan) -> h chunk (bf16, LD 832).
// Gate column layout: cols [0,1600) = z,f interleaved (z at 2h, f at 2h+1),
// cols [1600,2400) = o at 1600+h, rest pad. Layer 2 drops o (N=1664).
// Workspace ~77 MB.

typedef __bf16 bf16_t;
typedef __bf16 bf16x8 __attribute__((ext_vector_type(8)));
typedef float f32x4 __attribute__((ext_vector_type(4)));

#define T_SEQ 512
#define T_C 128
#define NCHUNK 4
#define BATCH 64
#define EMB 300
#define HID 800
#define LDH 832                 // h buffer leading dim (K padded for BK=64)
#define MC (T_C * BATCH)        // 8192 rows per chunk

__device__ __forceinline__ float fast_sigmoid(float x) {
  return 1.0f / (1.0f + __expf(-x));
}
__device__ __forceinline__ float fast_tanh(float x) {
  return 2.0f / (1.0f + __expf(-2.0f * x)) - 1.0f;
}
__device__ __forceinline__ float b2f(uint32_t u) {
  union { uint32_t i; float f; } x;
  x.i = u << 16;
  return x.f;
}

// ---- prep: all 3 weights: W [K,2400] fp32 -> Wt [Npad,Kpad] bf16, with
// output-row permutation n' = 2h+g for z/f (g=0,1), o kept at 1600+h. ----
__global__ __launch_bounds__(256) void transpose_cast_w3(
    const float* __restrict__ W0, const float* __restrict__ W1,
    const float* __restrict__ W2, bf16_t* __restrict__ T0,
    bf16_t* __restrict__ T1, bf16_t* __restrict__ T2) {
  const int z = blockIdx.z;
  const float* W = z == 0 ? W0 : (z == 1 ? W1 : W2);
  bf16_t* Wt = z == 0 ? T0 : (z == 1 ? T1 : T2);
  const int K = z == 0 ? 300 : 800;
  const int Kpad = z == 0 ? 320 : 832;
  const int Npad = z == 2 ? 1664 : 2432;
  const int hasO = (z != 2);
  const int i = blockIdx.x, j = blockIdx.y;
  if (i * 32 >= Npad || j * 32 >= Kpad) return;
  __shared__ float tile[32][33];
  const int tx = threadIdx.x & 31, ty = threadIdx.x >> 5;
#pragma unroll
  for (int r = 0; r < 32; r += 8) {
    const int k = j * 32 + ty + r;
    const int np = i * 32 + tx;
    int src = 0;
    bool valid = (k < K);
    if (np < 1600) src = (np & 1) * 800 + (np >> 1);
    else if (hasO && np < 2400) src = np;
    else valid = false;
    tile[ty + r][tx] = valid ? W[(size_t)k * 2400 + src] : 0.0f;
  }
  __syncthreads();
#pragma unroll
  for (int r = 0; r < 32; r += 8) {
    const int np = i * 32 + ty + r, k = j * 32 + tx;
    if (np < Npad && k < Kpad)
      Wt[(size_t)np * Kpad + k] = (bf16_t)tile[tx][ty + r];
  }
}

// ---- async 16B global->LDS (wave-uniform base + lane*16 layout) ----
__device__ __forceinline__ void stage16(const bf16_t* gp, bf16_t* lp) {
  __builtin_amdgcn_global_load_lds((__attribute__((address_space(1))) void*)gp,
                                   (__attribute__((address_space(3))) void*)lp,
                                   16, 0, 0);
}

// ---- bf16 MFMA GEMM, 128x128 tile, BK=64, raw bf16 out (no bias/act) ----
// A: bf16 [8192, aStride] (64|K) OR fp32 [8192, aStride] when aIsF32
// (converted+zero-padded to K during LDS staging). Bt [Npad,K] bf16.
// LDS staging XOR-swizzled: row r, LDS chunk c holds global chunk c^(r&7)
// (16B chunks) -> conflict-free ds_read_b128 fragment reads.
// XCD swizzle: linear block L -> XCD x=L%8 owns m-tiles [8x,8x+8).
__global__ __launch_bounds__(256, 4) void gemm_raw(const void* __restrict__ Ain,
                                                   const bf16_t* __restrict__ Bt,
                                                   bf16_t* __restrict__ G,
                                                   int K, int aStride, int ldg,
                                                   int aIsF32) {
  __shared__ __align__(16) bf16_t S[17920];  // staging 16384 el; Et 128*140
  bf16_t* As = S;          // [128][64] swizzled
  bf16_t* Bs = S + 8192;   // [128][64] swizzled
  const int tid = threadIdx.x;
  const int wave = tid >> 6, lane = tid & 63;
  const int wm = wave >> 1, wn = wave & 1;  // 2x2 waves of 64x64
  // XCD-aware remap: L%8 = XCD gets 8 consecutive m-tiles, all n-tiles.
  const int nT = gridDim.x;
  const int L = blockIdx.y * nT + blockIdx.x;
  const int xcd = L & 7, j = L >> 3;
  const int mBase = (xcd * 8 + j / nT) * 128;
  const int nBase = (j % nT) * 128;

  // staging: per matrix, 4 passes: row = (tid>>3)+32p, LDS chunk = tid&7,
  // global chunk = (tid&7) ^ (row&7). (row&7 invariant under +32p.)
  const int srow = tid >> 3;
  const int scolSw = ((tid & 7) ^ (srow & 7)) * 8;
  const size_t aBase = (size_t)(mBase + srow) * aStride + scolSw;
  const size_t bBase = (size_t)(nBase + srow) * K + scolSw;
  const int ldsOff = tid * 8;

  f32x4 acc[4][4];
#pragma unroll
  for (int mt = 0; mt < 4; ++mt)
#pragma unroll
    for (int nt = 0; nt < 4; ++nt) {
      f32x4 zz = {0.0f, 0.0f, 0.0f, 0.0f};
      acc[mt][nt] = zz;
    }

  const int fr = lane & 15, fq = lane >> 4;
  const int x0 = fr & 7;
  // LDS element offset of global chunk (kh*4+fq) in a row, post-swizzle:
  const int ckEl0 = ((0 * 4 + fq) ^ x0) * 8;
  const int ckEl1 = ((1 * 4 + fq) ^ x0) * 8;

  for (int k0 = 0; k0 < K; k0 += 64) {
    if (aIsF32) {
      // fp32 A staging: guarded vector loads + convert + ds_write_b128.
      const float* Af = (const float*)Ain;
      const int gc = scolSw + k0;
#pragma unroll
      for (int p = 0; p < 4; ++p) {
        const float* src = Af + aBase + (size_t)(32 * p) * aStride + k0;
        bf16x8 w;
        if (gc + 8 <= EMB) {
          const f32x4 v0 = *(const f32x4*)src;
          const f32x4 v1 = *(const f32x4*)(src + 4);
#pragma unroll
          for (int e = 0; e < 4; ++e) {
            w[e] = (bf16_t)v0[e];
            w[e + 4] = (bf16_t)v1[e];
          }
        } else {
#pragma unroll
          for (int e = 0; e < 8; ++e)
            w[e] = (bf16_t)((gc + e < EMB) ? src[e] : 0.0f);
        }
        *(bf16x8*)&As[ldsOff + p * 2048] = w;
      }
    } else {
      const bf16_t* Ab = (const bf16_t*)Ain;
#pragma unroll
      for (int p = 0; p < 4; ++p)
        stage16(Ab + aBase + (size_t)(32 * p) * aStride + k0,
                &As[ldsOff + p * 2048]);
    }
#pragma unroll
    for (int p = 0; p < 4; ++p)
      stage16(Bt + bBase + (size_t)(32 * p) * K + k0, &Bs[ldsOff + p * 2048]);
    __syncthreads();
#pragma unroll
    for (int kh = 0; kh < 2; ++kh) {
      const int ck = kh ? ckEl1 : ckEl0;
      bf16x8 af[4], bfv[4];
#pragma unroll
      for (int mt = 0; mt < 4; ++mt)
        af[mt] = *(const bf16x8*)&As[(wm * 64 + mt * 16 + fr) * 64 + ck];
#pragma unroll
      for (int nt = 0; nt < 4; ++nt)
        bfv[nt] = *(const bf16x8*)&Bs[(wn * 64 + nt * 16 + fr) * 64 + ck];
#pragma unroll
      for (int mt = 0; mt < 4; ++mt)
#pragma unroll
        for (int nt = 0; nt < 4; ++nt)
          acc[mt][nt] = __builtin_amdgcn_mfma_f32_16x16x32_bf16(
              af[mt], bfv[nt], acc[mt][nt], 0, 0, 0);
    }
    __syncthreads();
  }

  // epilogue: C/D layout col=lane&15, row=(lane>>4)*4+r. Full-tile LDS
  // transpose (Et[128][140]) then 128B/thread coalesced vector stores.
  bf16_t* Et = S;
#pragma unroll
  for (int mt = 0; mt < 4; ++mt)
#pragma unroll
    for (int nt = 0; nt < 4; ++nt)
#pragma unroll
      for (int r = 0; r < 4; ++r)
        Et[(wm * 64 + mt * 16 + fq * 4 + r) * 140 + wn * 64 + nt * 16 + fr] =
            (bf16_t)acc[mt][nt][r];
  __syncthreads();
  const int q = tid & 3, r0 = tid >> 2;  // quarter-row units (64B each)
#pragma unroll
  for (int hh = 0; hh < 2; ++hh) {
    const int row = r0 + hh * 64;
    const bf16_t* src = &Et[row * 140 + q * 32];
    bf16_t* dst = &G[(size_t)(mBase + row) * ldg + nBase + q * 32];
    *(bf16x8*)dst = *(const bf16x8*)src;
    *(bf16x8*)(dst + 8) = *(const bf16x8*)(src + 8);
    *(bf16x8*)(dst + 16) = *(const bf16x8*)(src + 16);
    *(bf16x8*)(dst + 24) = *(const bf16x8*)(src + 24);
  }
}

// ---- segment-parallel fo-pool scan over one T-chunk ----
// G bf16 RAW gates, zf-interleaved: z' at col 2h, f' at 2h+1, o' at 1600+h.
// Thread (chain, seg): 16 timesteps. Phase 1: dword (z,f) loads + activate +
// compose affine (A,B). Phase 2: 32 serial combiners via LDS. Phase 3:
// rescan, h_t = sigmoid(o'+bo)*c_t into Hout[row][h] (LD 832, pad zeroed).
__global__ __launch_bounds__(256) void scan_chunk_seg(
    const bf16_t* __restrict__ G, const float* __restrict__ bias,
    bf16_t* __restrict__ Hout, float* __restrict__ carry,
    float* __restrict__ outC, int ldg, int outOff, int writeH, int first,
    int last) {
  __shared__ float SA[8][32], SB[8][32], SC[8][32];
  const int chainLane = threadIdx.x & 31;
  const int seg = threadIdx.x >> 5;
  const int ch = blockIdx.x * 32 + chainLane;  // 0..51199
  const int b = ch / HID, h = ch - b * HID;
  const int t0 = seg * 16;
  const float bz = bias[h], bf = bias[h + 800];
  const float bo = writeH ? bias[h + 1600] : 0.0f;
  const int ldgh = ldg >> 1;
  const uint32_t* Gp = (const uint32_t*)G;

  float zr[16], fv[16];
#pragma unroll
  for (int j = 0; j < 16; ++j) {
    const uint32_t v = Gp[(size_t)((t0 + j) * BATCH + b) * ldgh + h];
    zr[j] = fast_tanh(b2f(v & 0xffffu) + bz);
    fv[j] = fast_sigmoid(b2f(v >> 16) + bf);
  }
  float A = 1.0f, Bacc = 0.0f;
#pragma unroll
  for (int j = 0; j < 16; ++j) {
    const float a = 1.0f - fv[j];
    A *= a;
    Bacc = fmaf(a, Bacc, fv[j] * zr[j]);
  }
  SA[seg][chainLane] = A;
  SB[seg][chainLane] = Bacc;
  __syncthreads();
  if (threadIdx.x < 32) {
    const int cc = blockIdx.x * 32 + threadIdx.x;
    float c = first ? 0.0f : carry[cc];
#pragma unroll
    for (int s = 0; s < 8; ++s) {
      SC[s][threadIdx.x] = c;
      c = fmaf(SA[s][threadIdx.x], c, SB[s][threadIdx.x]);
    }
    carry[cc] = c;
    if (last) {
      const int b2 = cc / HID, h2 = cc - b2 * HID;
      outC[b2 * 2400 + outOff + h2] = c;
    }
  }
  __syncthreads();
  if (!writeH) return;
  float c = SC[seg][chainLane];
#pragma unroll
  for (int j = 0; j < 16; ++j) {
    const size_t row = (size_t)((t0 + j) * BATCH + b);
    const float o = fast_sigmoid((float)G[row * ldg + 1600 + h] + bo);
    c = fmaf(fv[j], zr[j] - c, c);  // f*z + (1-f)*c
    Hout[row * LDH + h] = (bf16_t)(o * c);
    if (h >= 768) Hout[row * LDH + h + 32] = (bf16_t)0.0f;  // zero K-pad cols
  }
}

extern "C" void kernel_launch(void* const* d_in, const int* in_sizes, int n_in,
                              void* d_out, int out_size, void* d_ws, size_t ws_size,
                              hipStream_t stream) {
  const float* sent = (const float*)d_in[0];
  // d_in[1] = lengths: unused by the reference
  const float* W0 = (const float*)d_in[2];
  const float* b0 = (const float*)d_in[3];
  const float* W1 = (const float*)d_in[4];
  const float* b1 = (const float*)d_in[5];
  const float* W2 = (const float*)d_in[6];
  const float* b2 = (const float*)d_in[7];
  float* out = (float*)d_out;

  char* ws = (char*)d_ws;
  size_t off = 0;
  auto alloc = [&](size_t bytes) {
    void* p = ws + off;
    off += (bytes + 255) & ~(size_t)255;
    return p;
  };
  bf16_t* W0t = (bf16_t*)alloc((size_t)2432 * 320 * 2);  // 1.6 MB
  bf16_t* W1t = (bf16_t*)alloc((size_t)2432 * 832 * 2);  // 4.0 MB
  bf16_t* W2t = (bf16_t*)alloc((size_t)1664 * 832 * 2);  // 2.8 MB
  bf16_t* H0c = (bf16_t*)alloc((size_t)MC * LDH * 2);    // 13.6 MB
  bf16_t* H1c = (bf16_t*)alloc((size_t)MC * LDH * 2);    // 13.6 MB
  bf16_t* ZFO = (bf16_t*)alloc((size_t)MC * 2432 * 2);   // 39.8 MB
  float* C0 = (float*)alloc((size_t)BATCH * HID * 4);    // 205 KB
  float* C1 = (float*)alloc((size_t)BATCH * HID * 4);
  float* C2 = (float*)alloc((size_t)BATCH * HID * 4);
  if (off > ws_size) return;  // ws too small: fail verification, don't fault

  transpose_cast_w3<<<dim3(76, 26, 3), 256, 0, stream>>>(W0, W1, W2, W0t, W1t, W2t);

  for (int c = 0; c < NCHUNK; ++c) {
    const int first = (c == 0), last = (c == NCHUNK - 1);
    // layer 0: fp32 A staged+converted in-kernel (K=300 -> padded 320)
    gemm_raw<<<dim3(19, 64), 256, 0, stream>>>(
        sent + (size_t)c * MC * EMB, W0t, ZFO, 320, EMB, 2432, 1);
    scan_chunk_seg<<<1600, 256, 0, stream>>>(ZFO, b0, H0c, C0, out, 2432, 0, 1,
                                             first, last);
    // layer 1 (K=832 padded)
    gemm_raw<<<dim3(19, 64), 256, 0, stream>>>(H0c, W1t, ZFO, 832, 832, 2432, 0);
    scan_chunk_seg<<<1600, 256, 0, stream>>>(ZFO, b1, H1c, C1, out, 2432, 800,
                                             1, first, last);
    // layer 2: o-gate dead -> N=1664 (z,f only)
    gemm_raw<<<dim3(13, 64), 256, 0, stream>>>(H1c, W2t, ZFO, 832, 832, 1664, 0);
    scan_chunk_seg<<<1600, 256, 0, stream>>>(ZFO, b2, nullptr, C2, out, 1664,
                                             1600, 0, first, last);
  }
}

// Round 8
// 740.362 us; speedup vs baseline: 1.1223x; 1.1223x over previous
//
#include <hip/hip_runtime.h>
#include <hip/hip_bf16.h>
#include <cstdint>
#include <cstddef>

// QRNN encoder, 3 layers. T=512 B=64 E=300 H=800.
// b-major chunk layout (row = b*128 + t): a chain's whole 128-step history
// lives in ONE 128-row m-tile, so the fo-pool scan fuses into the GEMM
// epilogue (z,f never leave LDS). Per chunk, per layer:
//   gemm_scan: zf-GEMM (N=1664: z at col 2h, f at 2h+1) + in-LDS
//     segment-parallel scan -> c tile (bf16) + carry (+ final c to out)
//   gemm_hout: o-GEMM (N=896) + epilogue h = sigmoid(o'+bo) * c -> H chunk
// Layer 2 needs no o/h. GEMM: BK=64, XOR-swizzled LDS staging (0 bank
// conflicts), XCD-aware block swizzle, async global_load_lds staging.
// Workspace ~85 MB.

typedef __bf16 bf16_t;
typedef __bf16 bf16x8 __attribute__((ext_vector_type(8)));
typedef float f32x4 __attribute__((ext_vector_type(4)));

#define T_C 128
#define NCHUNK 4
#define BATCH 64
#define EMB 300
#define HID 800
#define LDH 832                 // h / c buffer leading dim
#define MC (T_C * BATCH)        // 8192 rows per chunk

__device__ __forceinline__ float fast_sigmoid(float x) {
  return 1.0f / (1.0f + __expf(-x));
}
__device__ __forceinline__ float fast_tanh(float x) {
  return 2.0f / (1.0f + __expf(-2.0f * x)) - 1.0f;
}

// ---- prep: sent [T*B rows t*64+b][300] fp32 -> A0 bf16 b-major chunks:
// dst row = c*8192 + b*128 + t, cols 0..319 (zero K-pad). ----
__global__ __launch_bounds__(256) void cast_reorder_a0(
    const float* __restrict__ X, bf16_t* __restrict__ Y) {
  int idx = blockIdx.x * 256 + threadIdx.x;
  if (idx >= 32768 * 320) return;
  int r = idx / 320, col = idx - r * 320;
  const int cc = r >> 13, b = (r >> 7) & 63, t = r & 127;
  const int src = (cc * 128 + t) * 64 + b;
  float v = (col < EMB) ? X[(size_t)src * EMB + col] : 0.0f;
  Y[idx] = (bf16_t)v;
}

// ---- prep: weights -> transposed bf16 buffers.
// zf (z=0,1,2): Wzf[1664][Kpad], row n: h=n>>1, g=n&1 -> src col g*800+h.
// o  (z=3,4):   Wo [896][Kpad],  row n=h -> src col 1600+h. ----
__global__ __launch_bounds__(256) void transpose_cast_w(
    const float* __restrict__ W0, const float* __restrict__ W1,
    const float* __restrict__ W2, bf16_t* __restrict__ Z0,
    bf16_t* __restrict__ Z1, bf16_t* __restrict__ Z2,
    bf16_t* __restrict__ O0, bf16_t* __restrict__ O1) {
  const int z = blockIdx.z;
  const float* W = (z == 0 || z == 3) ? W0 : ((z == 1 || z == 4) ? W1 : W2);
  bf16_t* Wt = z == 0 ? Z0 : (z == 1 ? Z1 : (z == 2 ? Z2 : (z == 3 ? O0 : O1)));
  const int K = (z == 0 || z == 3) ? 300 : 800;
  const int Kpad = (z == 0 || z == 3) ? 320 : 832;
  const int Npad = (z < 3) ? 1664 : 896;
  const int isZF = (z < 3);
  const int i = blockIdx.x, j = blockIdx.y;
  if (i * 32 >= Npad || j * 32 >= Kpad) return;
  __shared__ float tile[32][33];
  const int tx = threadIdx.x & 31, ty = threadIdx.x >> 5;
#pragma unroll
  for (int r = 0; r < 32; r += 8) {
    const int k = j * 32 + ty + r;
    const int n = i * 32 + tx;
    int src;
    bool valid = (k < K);
    if (isZF) {
      const int h = n >> 1;
      src = (n & 1) * 800 + h;
      valid = valid && (h < 800);
    } else {
      src = 1600 + n;
      valid = valid && (n < 800);
    }
    tile[ty + r][tx] = valid ? W[(size_t)k * 2400 + src] : 0.0f;
  }
  __syncthreads();
#pragma unroll
  for (int r = 0; r < 32; r += 8) {
    const int n = i * 32 + ty + r, k = j * 32 + tx;
    if (n < Npad && k < Kpad)
      Wt[(size_t)n * Kpad + k] = (bf16_t)tile[tx][ty + r];
  }
}

// ---- async 16B global->LDS (wave-uniform base + lane*16 layout) ----
__device__ __forceinline__ void stage16(const bf16_t* gp, bf16_t* lp) {
  __builtin_amdgcn_global_load_lds((__attribute__((address_space(1))) void*)gp,
                                   (__attribute__((address_space(3))) void*)lp,
                                   16, 0, 0);
}

// Shared GEMM core: computes 128x128 tile of A@Wt^T into Et[128][140] (bf16).
// XOR-swizzled staging, conflict-free ds_read_b128 fragment reads.
__device__ __forceinline__ void gemm_tile_to_lds(
    const bf16_t* __restrict__ A, const bf16_t* __restrict__ Bt,
    bf16_t* __restrict__ S, int K, int mBase, int nBase) {
  bf16_t* As = S;
  bf16_t* Bs = S + 8192;
  const int tid = threadIdx.x;
  const int wave = tid >> 6, lane = tid & 63;
  const int wm = wave >> 1, wn = wave & 1;
  const int srow = tid >> 3;
  const int scolSw = ((tid & 7) ^ (srow & 7)) * 8;
  const size_t aBase = (size_t)(mBase + srow) * K + scolSw;
  const size_t bBase = (size_t)(nBase + srow) * K + scolSw;
  const int ldsOff = tid * 8;

  f32x4 acc[4][4];
#pragma unroll
  for (int mt = 0; mt < 4; ++mt)
#pragma unroll
    for (int nt = 0; nt < 4; ++nt) {
      f32x4 zz = {0.0f, 0.0f, 0.0f, 0.0f};
      acc[mt][nt] = zz;
    }

  const int fr = lane & 15, fq = lane >> 4;
  const int x0 = fr & 7;
  const int ckEl0 = ((0 * 4 + fq) ^ x0) * 8;
  const int ckEl1 = ((1 * 4 + fq) ^ x0) * 8;

  for (int k0 = 0; k0 < K; k0 += 64) {
#pragma unroll
    for (int p = 0; p < 4; ++p)
      stage16(A + aBase + (size_t)(32 * p) * K + k0, &As[ldsOff + p * 2048]);
#pragma unroll
    for (int p = 0; p < 4; ++p)
      stage16(Bt + bBase + (size_t)(32 * p) * K + k0, &Bs[ldsOff + p * 2048]);
    __syncthreads();
#pragma unroll
    for (int kh = 0; kh < 2; ++kh) {
      const int ck = kh ? ckEl1 : ckEl0;
      bf16x8 af[4], bfv[4];
#pragma unroll
      for (int mt = 0; mt < 4; ++mt)
        af[mt] = *(const bf16x8*)&As[(wm * 64 + mt * 16 + fr) * 64 + ck];
#pragma unroll
      for (int nt = 0; nt < 4; ++nt)
        bfv[nt] = *(const bf16x8*)&Bs[(wn * 64 + nt * 16 + fr) * 64 + ck];
#pragma unroll
      for (int mt = 0; mt < 4; ++mt)
#pragma unroll
        for (int nt = 0; nt < 4; ++nt)
          acc[mt][nt] = __builtin_amdgcn_mfma_f32_16x16x32_bf16(
              af[mt], bfv[nt], acc[mt][nt], 0, 0, 0);
    }
    __syncthreads();
  }
  // C/D layout col=lane&15, row=(lane>>4)*4+r -> Et[row][col], stride 140.
  bf16_t* Et = S;
#pragma unroll
  for (int mt = 0; mt < 4; ++mt)
#pragma unroll
    for (int nt = 0; nt < 4; ++nt)
#pragma unroll
      for (int r = 0; r < 4; ++r)
        Et[(wm * 64 + mt * 16 + fq * 4 + r) * 140 + wn * 64 + nt * 16 + fr] =
            (bf16_t)acc[mt][nt][r];
  __syncthreads();
}

// ---- kernel A: zf-GEMM + fused fo-pool scan over the in-LDS tile ----
// Grid (13, 64). m-tile = batch b; n-tile covers h in [64j, 64j+64).
// Et[t][2hl+g] holds raw z',f'. Scan: 64 chains x 4 segments of 32 steps.
__global__ __launch_bounds__(256, 3) void gemm_scan(
    const bf16_t* __restrict__ A, const bf16_t* __restrict__ Wzf,
    const float* __restrict__ bias, bf16_t* __restrict__ Cbuf,
    float* __restrict__ carry, float* __restrict__ outC, int K, int outOff,
    int writeC, int first, int last) {
  __shared__ __align__(16) bf16_t S[17920];
  __shared__ float SA[4][64], SB[4][64], SC[4][64];
  const int nT = gridDim.x;  // 13
  const int L = blockIdx.y * nT + blockIdx.x;
  const int xcd = L & 7, j = L >> 3;
  const int b = xcd * 8 + j / nT;       // m-tile = batch
  const int ntile = j % nT;
  gemm_tile_to_lds(A, Wzf, S, K, b * 128, ntile * 128);

  const bf16_t* Et = S;
  const int tid = threadIdx.x;
  const int hl = tid & 63, s = tid >> 6;
  const int h = ntile * 64 + hl;
  const bool hOK = (h < HID);
  const int hb = hOK ? h : 0;
  const float bz = bias[hb], bf = bias[hb + 800];

  // phase 1: per-segment affine composition (a=1-f, b=f*z)
  float Aa = 1.0f, Bb = 0.0f;
#pragma unroll
  for (int q = 0; q < 32; ++q) {
    const int t = s * 32 + q;
    const float zv = fast_tanh((float)Et[t * 140 + 2 * hl] + bz);
    const float fv = fast_sigmoid((float)Et[t * 140 + 2 * hl + 1] + bf);
    const float a = 1.0f - fv;
    Aa *= a;
    Bb = fmaf(a, Bb, fv * zv);
  }
  SA[s][hl] = Aa;
  SB[s][hl] = Bb;
  __syncthreads();
  // phase 2: serial combine over 4 segments, one thread per chain
  if (tid < 64) {
    const int h2 = ntile * 64 + tid;
    const bool ok2 = (h2 < HID);
    float c = (first || !ok2) ? 0.0f : carry[b * HID + h2];
#pragma unroll
    for (int ss = 0; ss < 4; ++ss) {
      SC[ss][tid] = c;
      c = fmaf(SA[ss][tid], c, SB[ss][tid]);
    }
    if (ok2) {
      carry[b * HID + h2] = c;
      if (last) outC[b * 2400 + outOff + h2] = c;
    }
  }
  __syncthreads();
  // phase 3: rescan, write c tile (bf16) for the o-kernel
  if (!writeC) return;
  float c = SC[s][hl];
#pragma unroll
  for (int q = 0; q < 32; ++q) {
    const int t = s * 32 + q;
    const float zv = fast_tanh((float)Et[t * 140 + 2 * hl] + bz);
    const float fv = fast_sigmoid((float)Et[t * 140 + 2 * hl + 1] + bf);
    c = fmaf(fv, zv - c, c);  // f*z + (1-f)*c
    if (hOK) Cbuf[(size_t)(b * 128 + t) * LDH + h] = (bf16_t)c;
  }
}

// ---- kernel B: o-GEMM + epilogue h = sigmoid(o'+bo) * c -> H chunk ----
// Grid (7, 64). n-tile covers h in [128j, 128j+128); h>=800 pads written 0.
__global__ __launch_bounds__(256, 3) void gemm_hout(
    const bf16_t* __restrict__ A, const bf16_t* __restrict__ Wo,
    const float* __restrict__ bias, const bf16_t* __restrict__ Cbuf,
    bf16_t* __restrict__ Hout, int K) {
  __shared__ __align__(16) bf16_t S[17920];
  const int nT = gridDim.x;  // 7
  const int L = blockIdx.y * nT + blockIdx.x;
  const int xcd = L & 7, j = L >> 3;
  const int b = xcd * 8 + j / nT;
  const int ntile = j % nT;
  gemm_tile_to_lds(A, Wo, S, K, b * 128, ntile * 128);

  const bf16_t* Et = S;
  const int tid = threadIdx.x;
  const int q = tid & 3, r0 = tid >> 2;
  const int hBase = ntile * 128 + q * 32;
  if (hBase >= LDH) return;  // h >= 832: beyond H buffer, nothing to write
  const bool zone = (hBase < HID);  // else pure zero-pad zone [800,832)
  float bo[32];
  if (zone) {
#pragma unroll
    for (int e = 0; e < 32; ++e) bo[e] = bias[1600 + hBase + e];
  }
#pragma unroll
  for (int hh = 0; hh < 2; ++hh) {
    const int t = r0 + hh * 64;
    const size_t row = (size_t)(b * 128 + t);
    bf16x8 outv[4];
    if (zone) {
      const bf16x8* cv = (const bf16x8*)&Cbuf[row * LDH + hBase];
#pragma unroll
      for (int v = 0; v < 4; ++v) {
        const bf16x8 cc = cv[v];
#pragma unroll
        for (int e = 0; e < 8; ++e) {
          const float o =
              fast_sigmoid((float)Et[t * 140 + q * 32 + v * 8 + e] + bo[v * 8 + e]);
          outv[v][e] = (bf16_t)(o * (float)cc[e]);
        }
      }
    } else {
#pragma unroll
      for (int v = 0; v < 4; ++v)
#pragma unroll
        for (int e = 0; e < 8; ++e) outv[v][e] = (bf16_t)0.0f;
    }
    bf16_t* dst = &Hout[row * LDH + hBase];
#pragma unroll
    for (int v = 0; v < 4; ++v) *(bf16x8*)(dst + v * 8) = outv[v];
  }
}

extern "C" void kernel_launch(void* const* d_in, const int* in_sizes, int n_in,
                              void* d_out, int out_size, void* d_ws, size_t ws_size,
                              hipStream_t stream) {
  const float* sent = (const float*)d_in[0];
  // d_in[1] = lengths: unused by the reference
  const float* W0 = (const float*)d_in[2];
  const float* b0 = (const float*)d_in[3];
  const float* W1 = (const float*)d_in[4];
  const float* b1 = (const float*)d_in[5];
  const float* W2 = (const float*)d_in[6];
  const float* b2 = (const float*)d_in[7];
  float* out = (float*)d_out;

  char* ws = (char*)d_ws;
  size_t off = 0;
  auto alloc = [&](size_t bytes) {
    void* p = ws + off;
    off += (bytes + 255) & ~(size_t)255;
    return p;
  };
  bf16_t* Wzf0 = (bf16_t*)alloc((size_t)1664 * 320 * 2);  // 1.1 MB
  bf16_t* Wzf1 = (bf16_t*)alloc((size_t)1664 * 832 * 2);  // 2.8 MB
  bf16_t* Wzf2 = (bf16_t*)alloc((size_t)1664 * 832 * 2);  // 2.8 MB
  bf16_t* Wo0 = (bf16_t*)alloc((size_t)896 * 320 * 2);    // 0.6 MB
  bf16_t* Wo1 = (bf16_t*)alloc((size_t)896 * 832 * 2);    // 1.5 MB
  bf16_t* A0 = (bf16_t*)alloc((size_t)32768 * 320 * 2);   // 21.0 MB
  bf16_t* H0c = (bf16_t*)alloc((size_t)MC * LDH * 2);     // 13.6 MB
  bf16_t* H1c = (bf16_t*)alloc((size_t)MC * LDH * 2);     // 13.6 MB
  bf16_t* Cb = (bf16_t*)alloc((size_t)MC * LDH * 2);      // 13.6 MB
  float* car0 = (float*)alloc((size_t)BATCH * HID * 4);   // 205 KB
  float* car1 = (float*)alloc((size_t)BATCH * HID * 4);
  float* car2 = (float*)alloc((size_t)BATCH * HID * 4);
  if (off > ws_size) return;  // ws too small: fail verification, don't fault

  cast_reorder_a0<<<(32768 * 320 + 255) / 256, 256, 0, stream>>>(sent, A0);
  transpose_cast_w<<<dim3(52, 26, 5), 256, 0, stream>>>(W0, W1, W2, Wzf0, Wzf1,
                                                        Wzf2, Wo0, Wo1);

  for (int c = 0; c < NCHUNK; ++c) {
    const int first = (c == 0), last = (c == NCHUNK - 1);
    const bf16_t* A0c = A0 + (size_t)c * MC * 320;
    // layer 0 (K=320)
    gemm_scan<<<dim3(13, 64), 256, 0, stream>>>(A0c, Wzf0, b0, Cb, car0, out,
                                                320, 0, 1, first, last);
    gemm_hout<<<dim3(7, 64), 256, 0, stream>>>(A0c, Wo0, b0, Cb, H0c, 320);
    // layer 1 (K=832 padded)
    gemm_scan<<<dim3(13, 64), 256, 0, stream>>>(H0c, Wzf1, b1, Cb, car1, out,
                                                832, 800, 1, first, last);
    gemm_hout<<<dim3(7, 64), 256, 0, stream>>>(H0c, Wo1, b1, Cb, H1c, 832);
    // layer 2: o-gate dead -> zf only, no c tile
    gemm_scan<<<dim3(13, 64), 256, 0, stream>>>(H1c, Wzf2, b2, nullptr, car2,
                                                out, 832, 1600, 0, first, last);
  }
}

// Round 9
// 674.233 us; speedup vs baseline: 1.2324x; 1.0981x over previous
//
#include <hip/hip_runtime.h>
#include <hip/hip_bf16.h>
#include <cstdint>
#include <cstddef>

// QRNN encoder, 3 layers. T=512 B=64 E=300 H=800.
// b-major chunk layout (row = b*128 + t): a chain's whole 128-step history
// lives in ONE 128-row m-tile, so the fo-pool scan fuses into the GEMM
// epilogue (z,f never leave LDS). Per chunk, per layer:
//   gemm_scan: zf-GEMM (N=1664: z at col 2h, f at 2h+1) + in-LDS
//     segment-parallel scan (affine coeffs register-cached, phase 3 is a
//     pure fma chain) -> c tile (bf16) + carry (+ final c to out)
//   gemm_hout: o-GEMM (N=896) + epilogue h = sigmoid(o'+bo) * c -> H chunk
// Layer 2 needs no o/h. GEMM: BK=64, XOR-swizzled LDS staging (0 bank
// conflicts), XCD-aware block swizzle, async global_load_lds staging.
// Workspace ~85 MB.

typedef __bf16 bf16_t;
typedef __bf16 bf16x8 __attribute__((ext_vector_type(8)));
typedef float f32x4 __attribute__((ext_vector_type(4)));

#define T_C 128
#define NCHUNK 4
#define BATCH 64
#define EMB 300
#define HID 800
#define LDH 832                 // h / c buffer leading dim
#define MC (T_C * BATCH)        // 8192 rows per chunk

__device__ __forceinline__ float fast_sigmoid(float x) {
  return 1.0f / (1.0f + __expf(-x));
}
__device__ __forceinline__ float fast_tanh(float x) {
  return 2.0f / (1.0f + __expf(-2.0f * x)) - 1.0f;
}
__device__ __forceinline__ float b2f(uint32_t u) {
  union { uint32_t i; float f; } x;
  x.i = u << 16;
  return x.f;
}

// ---- prep: sent [T*B rows t*64+b][300] fp32 -> A0 bf16 b-major chunks:
// dst row = c*8192 + b*128 + t, cols 0..319 (zero K-pad). ----
__global__ __launch_bounds__(256) void cast_reorder_a0(
    const float* __restrict__ X, bf16_t* __restrict__ Y) {
  int idx = blockIdx.x * 256 + threadIdx.x;
  if (idx >= 32768 * 320) return;
  int r = idx / 320, col = idx - r * 320;
  const int cc = r >> 13, b = (r >> 7) & 63, t = r & 127;
  const int src = (cc * 128 + t) * 64 + b;
  float v = (col < EMB) ? X[(size_t)src * EMB + col] : 0.0f;
  Y[idx] = (bf16_t)v;
}

// ---- prep: weights -> transposed bf16 buffers.
// zf (z=0,1,2): Wzf[1664][Kpad], row n: h=n>>1, g=n&1 -> src col g*800+h.
// o  (z=3,4):   Wo [896][Kpad],  row n=h -> src col 1600+h. ----
__global__ __launch_bounds__(256) void transpose_cast_w(
    const float* __restrict__ W0, const float* __restrict__ W1,
    const float* __restrict__ W2, bf16_t* __restrict__ Z0,
    bf16_t* __restrict__ Z1, bf16_t* __restrict__ Z2,
    bf16_t* __restrict__ O0, bf16_t* __restrict__ O1) {
  const int z = blockIdx.z;
  const float* W = (z == 0 || z == 3) ? W0 : ((z == 1 || z == 4) ? W1 : W2);
  bf16_t* Wt = z == 0 ? Z0 : (z == 1 ? Z1 : (z == 2 ? Z2 : (z == 3 ? O0 : O1)));
  const int K = (z == 0 || z == 3) ? 300 : 800;
  const int Kpad = (z == 0 || z == 3) ? 320 : 832;
  const int Npad = (z < 3) ? 1664 : 896;
  const int isZF = (z < 3);
  const int i = blockIdx.x, j = blockIdx.y;
  if (i * 32 >= Npad || j * 32 >= Kpad) return;
  __shared__ float tile[32][33];
  const int tx = threadIdx.x & 31, ty = threadIdx.x >> 5;
#pragma unroll
  for (int r = 0; r < 32; r += 8) {
    const int k = j * 32 + ty + r;
    const int n = i * 32 + tx;
    int src;
    bool valid = (k < K);
    if (isZF) {
      const int h = n >> 1;
      src = (n & 1) * 800 + h;
      valid = valid && (h < 800);
    } else {
      src = 1600 + n;
      valid = valid && (n < 800);
    }
    tile[ty + r][tx] = valid ? W[(size_t)k * 2400 + src] : 0.0f;
  }
  __syncthreads();
#pragma unroll
  for (int r = 0; r < 32; r += 8) {
    const int n = i * 32 + ty + r, k = j * 32 + tx;
    if (n < Npad && k < Kpad)
      Wt[(size_t)n * Kpad + k] = (bf16_t)tile[tx][ty + r];
  }
}

// ---- async 16B global->LDS (wave-uniform base + lane*16 layout) ----
__device__ __forceinline__ void stage16(const bf16_t* gp, bf16_t* lp) {
  __builtin_amdgcn_global_load_lds((__attribute__((address_space(1))) void*)gp,
                                   (__attribute__((address_space(3))) void*)lp,
                                   16, 0, 0);
}

// Shared GEMM core: computes 128x128 tile of A@Wt^T into Et[128][140] (bf16).
// XOR-swizzled staging, conflict-free ds_read_b128 fragment reads.
__device__ __forceinline__ void gemm_tile_to_lds(
    const bf16_t* __restrict__ A, const bf16_t* __restrict__ Bt,
    bf16_t* __restrict__ S, int K, int mBase, int nBase) {
  bf16_t* As = S;
  bf16_t* Bs = S + 8192;
  const int tid = threadIdx.x;
  const int wave = tid >> 6, lane = tid & 63;
  const int wm = wave >> 1, wn = wave & 1;
  const int srow = tid >> 3;
  const int scolSw = ((tid & 7) ^ (srow & 7)) * 8;
  const size_t aBase = (size_t)(mBase + srow) * K + scolSw;
  const size_t bBase = (size_t)(nBase + srow) * K + scolSw;
  const int ldsOff = tid * 8;

  f32x4 acc[4][4];
#pragma unroll
  for (int mt = 0; mt < 4; ++mt)
#pragma unroll
    for (int nt = 0; nt < 4; ++nt) {
      f32x4 zz = {0.0f, 0.0f, 0.0f, 0.0f};
      acc[mt][nt] = zz;
    }

  const int fr = lane & 15, fq = lane >> 4;
  const int x0 = fr & 7;
  const int ckEl0 = ((0 * 4 + fq) ^ x0) * 8;
  const int ckEl1 = ((1 * 4 + fq) ^ x0) * 8;

  for (int k0 = 0; k0 < K; k0 += 64) {
#pragma unroll
    for (int p = 0; p < 4; ++p)
      stage16(A + aBase + (size_t)(32 * p) * K + k0, &As[ldsOff + p * 2048]);
#pragma unroll
    for (int p = 0; p < 4; ++p)
      stage16(Bt + bBase + (size_t)(32 * p) * K + k0, &Bs[ldsOff + p * 2048]);
    __syncthreads();
#pragma unroll
    for (int kh = 0; kh < 2; ++kh) {
      const int ck = kh ? ckEl1 : ckEl0;
      bf16x8 af[4], bfv[4];
#pragma unroll
      for (int mt = 0; mt < 4; ++mt)
        af[mt] = *(const bf16x8*)&As[(wm * 64 + mt * 16 + fr) * 64 + ck];
#pragma unroll
      for (int nt = 0; nt < 4; ++nt)
        bfv[nt] = *(const bf16x8*)&Bs[(wn * 64 + nt * 16 + fr) * 64 + ck];
#pragma unroll
      for (int mt = 0; mt < 4; ++mt)
#pragma unroll
        for (int nt = 0; nt < 4; ++nt)
          acc[mt][nt] = __builtin_amdgcn_mfma_f32_16x16x32_bf16(
              af[mt], bfv[nt], acc[mt][nt], 0, 0, 0);
    }
    __syncthreads();
  }
  // C/D layout col=lane&15, row=(lane>>4)*4+r -> Et[row][col], stride 140.
  bf16_t* Et = S;
#pragma unroll
  for (int mt = 0; mt < 4; ++mt)
#pragma unroll
    for (int nt = 0; nt < 4; ++nt)
#pragma unroll
      for (int r = 0; r < 4; ++r)
        Et[(wm * 64 + mt * 16 + fq * 4 + r) * 140 + wn * 64 + nt * 16 + fr] =
            (bf16_t)acc[mt][nt][r];
  __syncthreads();
}

// ---- kernel A: zf-GEMM + fused fo-pool scan over the in-LDS tile ----
// Grid (13, 64). m-tile = batch b; n-tile covers h in [64j, 64j+64).
// Et[t][2hl+g] holds raw z',f'. Scan: 64 chains x 4 segments of 32 steps.
// Phase 1 caches a=1-f, b=f*z in registers; phase 3 is a pure fma chain.
__global__ __launch_bounds__(256, 3) void gemm_scan(
    const bf16_t* __restrict__ A, const bf16_t* __restrict__ Wzf,
    const float* __restrict__ bias, bf16_t* __restrict__ Cbuf,
    float* __restrict__ carry, float* __restrict__ outC, int K, int outOff,
    int writeC, int first, int last) {
  __shared__ __align__(16) bf16_t S[17920];
  __shared__ float SA[4][64], SB[4][64], SC[4][64];
  const int nT = gridDim.x;  // 13
  const int L = blockIdx.y * nT + blockIdx.x;
  const int xcd = L & 7, j = L >> 3;
  const int b = xcd * 8 + j / nT;       // m-tile = batch
  const int ntile = j % nT;
  gemm_tile_to_lds(A, Wzf, S, K, b * 128, ntile * 128);

  const uint32_t* Ep = (const uint32_t*)S;  // Et dwords: idx t*70+hl = (z,f)
  const int tid = threadIdx.x;
  const int hl = tid & 63, s = tid >> 6;
  const int h = ntile * 64 + hl;
  const bool hOK = (h < HID);
  const int hb = hOK ? h : 0;
  const float bz = bias[hb], bf = bias[hb + 800];

  // phase 1: activate once, cache affine coeffs, compose segment map
  float av[32], bv[32];
  float Aa = 1.0f, Bb = 0.0f;
#pragma unroll
  for (int q = 0; q < 32; ++q) {
    const int t = s * 32 + q;
    const uint32_t v = Ep[t * 70 + hl];
    const float zv = fast_tanh(b2f(v & 0xffffu) + bz);
    const float fv = fast_sigmoid(b2f(v >> 16) + bf);
    av[q] = 1.0f - fv;
    bv[q] = fv * zv;
    Aa *= av[q];
    Bb = fmaf(av[q], Bb, bv[q]);
  }
  SA[s][hl] = Aa;
  SB[s][hl] = Bb;
  __syncthreads();
  // phase 2: serial combine over 4 segments, one thread per chain
  if (tid < 64) {
    const int h2 = ntile * 64 + tid;
    const bool ok2 = (h2 < HID);
    float c = (first || !ok2) ? 0.0f : carry[b * HID + h2];
#pragma unroll
    for (int ss = 0; ss < 4; ++ss) {
      SC[ss][tid] = c;
      c = fmaf(SA[ss][tid], c, SB[ss][tid]);
    }
    if (ok2) {
      carry[b * HID + h2] = c;
      if (last) outC[b * 2400 + outOff + h2] = c;
    }
  }
  __syncthreads();
  // phase 3: pure fma rescan from registers, write c tile (bf16)
  if (!writeC) return;
  float c = SC[s][hl];
#pragma unroll
  for (int q = 0; q < 32; ++q) {
    const int t = s * 32 + q;
    c = fmaf(av[q], c, bv[q]);  // a*c + b == f*z + (1-f)*c
    if (hOK) Cbuf[(size_t)(b * 128 + t) * LDH + h] = (bf16_t)c;
  }
}

// ---- kernel B: o-GEMM + epilogue h = sigmoid(o'+bo) * c -> H chunk ----
// Grid (7, 64). n-tile covers h in [128j, 128j+128); h>=800 pads written 0.
__global__ __launch_bounds__(256, 3) void gemm_hout(
    const bf16_t* __restrict__ A, const bf16_t* __restrict__ Wo,
    const float* __restrict__ bias, const bf16_t* __restrict__ Cbuf,
    bf16_t* __restrict__ Hout, int K) {
  __shared__ __align__(16) bf16_t S[17920];
  const int nT = gridDim.x;  // 7
  const int L = blockIdx.y * nT + blockIdx.x;
  const int xcd = L & 7, j = L >> 3;
  const int b = xcd * 8 + j / nT;
  const int ntile = j % nT;
  gemm_tile_to_lds(A, Wo, S, K, b * 128, ntile * 128);

  const bf16_t* Et = S;
  const int tid = threadIdx.x;
  const int q = tid & 3, r0 = tid >> 2;
  const int hBase = ntile * 128 + q * 32;
  if (hBase >= LDH) return;  // h >= 832: beyond H buffer, nothing to write
  const bool zone = (hBase < HID);  // else pure zero-pad zone [800,832)
  float bo[32];
  if (zone) {
#pragma unroll
    for (int e = 0; e < 32; ++e) bo[e] = bias[1600 + hBase + e];
  }
#pragma unroll
  for (int hh = 0; hh < 2; ++hh) {
    const int t = r0 + hh * 64;
    const size_t row = (size_t)(b * 128 + t);
    bf16x8 outv[4];
    if (zone) {
      const bf16x8* cv = (const bf16x8*)&Cbuf[row * LDH + hBase];
#pragma unroll
      for (int v = 0; v < 4; ++v) {
        const bf16x8 cc = cv[v];
#pragma unroll
        for (int e = 0; e < 8; ++e) {
          const float o =
              fast_sigmoid((float)Et[t * 140 + q * 32 + v * 8 + e] + bo[v * 8 + e]);
          outv[v][e] = (bf16_t)(o * (float)cc[e]);
        }
      }
    } else {
#pragma unroll
      for (int v = 0; v < 4; ++v)
#pragma unroll
        for (int e = 0; e < 8; ++e) outv[v][e] = (bf16_t)0.0f;
    }
    bf16_t* dst = &Hout[row * LDH + hBase];
#pragma unroll
    for (int v = 0; v < 4; ++v) *(bf16x8*)(dst + v * 8) = outv[v];
  }
}

extern "C" void kernel_launch(void* const* d_in, const int* in_sizes, int n_in,
                              void* d_out, int out_size, void* d_ws, size_t ws_size,
                              hipStream_t stream) {
  const float* sent = (const float*)d_in[0];
  // d_in[1] = lengths: unused by the reference
  const float* W0 = (const float*)d_in[2];
  const float* b0 = (const float*)d_in[3];
  const float* W1 = (const float*)d_in[4];
  const float* b1 = (const float*)d_in[5];
  const float* W2 = (const float*)d_in[6];
  const float* b2 = (const float*)d_in[7];
  float* out = (float*)d_out;

  char* ws = (char*)d_ws;
  size_t off = 0;
  auto alloc = [&](size_t bytes) {
    void* p = ws + off;
    off += (bytes + 255) & ~(size_t)255;
    return p;
  };
  bf16_t* Wzf0 = (bf16_t*)alloc((size_t)1664 * 320 * 2);  // 1.1 MB
  bf16_t* Wzf1 = (bf16_t*)alloc((size_t)1664 * 832 * 2);  // 2.8 MB
  bf16_t* Wzf2 = (bf16_t*)alloc((size_t)1664 * 832 * 2);  // 2.8 MB
  bf16_t* Wo0 = (bf16_t*)alloc((size_t)896 * 320 * 2);    // 0.6 MB
  bf16_t* Wo1 = (bf16_t*)alloc((size_t)896 * 832 * 2);    // 1.5 MB
  bf16_t* A0 = (bf16_t*)alloc((size_t)32768 * 320 * 2);   // 21.0 MB
  bf16_t* H0c = (bf16_t*)alloc((size_t)MC * LDH * 2);     // 13.6 MB
  bf16_t* H1c = (bf16_t*)alloc((size_t)MC * LDH * 2);     // 13.6 MB
  bf16_t* Cb = (bf16_t*)alloc((size_t)MC * LDH * 2);      // 13.6 MB
  float* car0 = (float*)alloc((size_t)BATCH * HID * 4);   // 205 KB
  float* car1 = (float*)alloc((size_t)BATCH * HID * 4);
  float* car2 = (float*)alloc((size_t)BATCH * HID * 4);
  if (off > ws_size) return;  // ws too small: fail verification, don't fault

  cast_reorder_a0<<<(32768 * 320 + 255) / 256, 256, 0, stream>>>(sent, A0);
  transpose_cast_w<<<dim3(52, 26, 5), 256, 0, stream>>>(W0, W1, W2, Wzf0, Wzf1,
                                                        Wzf2, Wo0, Wo1);

  for (int c = 0; c < NCHUNK; ++c) {
    const int first = (c == 0), last = (c == NCHUNK - 1);
    const bf16_t* A0c = A0 + (size_t)c * MC * 320;
    // layer 0 (K=320)
    gemm_scan<<<dim3(13, 64), 256, 0, stream>>>(A0c, Wzf0, b0, Cb, car0, out,
                                                320, 0, 1, first, last);
    gemm_hout<<<dim3(7, 64), 256, 0, stream>>>(A0c, Wo0, b0, Cb, H0c, 320);
    // layer 1 (K=832 padded)
    gemm_scan<<<dim3(13, 64), 256, 0, stream>>>(H0c, Wzf1, b1, Cb, car1, out,
                                                832, 800, 1, first, last);
    gemm_hout<<<dim3(7, 64), 256, 0, stream>>>(H0c, Wo1, b1, Cb, H1c, 832);
    // layer 2: o-gate dead -> zf only, no c tile
    gemm_scan<<<dim3(13, 64), 256, 0, stream>>>(H1c, Wzf2, b2, nullptr, car2,
                                                out, 832, 1600, 0, first, last);
  }
}

// Round 10
// 575.305 us; speedup vs baseline: 1.4443x; 1.1720x over previous
//
#include <hip/hip_runtime.h>
#include <hip/hip_bf16.h>
#include <cstdint>
#include <cstddef>

// QRNN encoder, 3 layers. T=512 B=64 E=300 H=800.
// b-major chunk layout (row = b*128 + t): a chain's whole 128-step history
// lives in ONE 128-row m-tile. Fully fused per (chunk, layer):
//   gemm_scan_h (L0/L1): 128x192 GEMM tile per block — z at col 2hl, f at
//     2hl+1 (cols 0..127), o at 128+hl (cols 128..191) for 64 h-chains —
//     + in-LDS segment-parallel fo-pool scan (affine coeffs in registers)
//     + h = sigmoid(o'+bo)*c epilogue -> H chunk + carry (+ c_last to out).
//   gemm_scan_c (L2): zf-only 128x128 tile, scan, carry/out only.
// GEMM: BK=64, XOR-swizzled LDS staging (0 bank conflicts), XCD-aware block
// swizzle, async global_load_lds. Workspace ~60 MB.

typedef __bf16 bf16_t;
typedef __bf16 bf16x8 __attribute__((ext_vector_type(8)));
typedef float f32x4 __attribute__((ext_vector_type(4)));

#define T_C 128
#define NCHUNK 4
#define BATCH 64
#define EMB 300
#define HID 800
#define LDH 832                 // h buffer leading dim (K-pad for BK=64)
#define MC (T_C * BATCH)        // 8192 rows per chunk

__device__ __forceinline__ float fast_sigmoid(float x) {
  return 1.0f / (1.0f + __expf(-x));
}
__device__ __forceinline__ float fast_tanh(float x) {
  return 2.0f / (1.0f + __expf(-2.0f * x)) - 1.0f;
}
__device__ __forceinline__ float b2f(uint32_t u) {
  union { uint32_t i; float f; } x;
  x.i = u << 16;
  return x.f;
}

// ---- prep: sent [T*B rows t*64+b][300] fp32 -> A0 bf16 b-major chunks:
// dst row = c*8192 + b*128 + t, cols 0..319 (zero K-pad). ----
__global__ __launch_bounds__(256) void cast_reorder_a0(
    const float* __restrict__ X, bf16_t* __restrict__ Y) {
  int idx = blockIdx.x * 256 + threadIdx.x;
  if (idx >= 32768 * 320) return;
  int r = idx / 320, col = idx - r * 320;
  const int cc = r >> 13, b = (r >> 7) & 63, t = r & 127;
  const int src = (cc * 128 + t) * 64 + b;
  float v = (col < EMB) ? X[(size_t)src * EMB + col] : 0.0f;
  Y[idx] = (bf16_t)v;
}

// ---- prep: weights -> transposed bf16 buffers.
// Merged zfo (z=0,1): Wm[2496][Kpad]; row n: tile j=n/192, r=n%192;
//   r<128: h=64j+(r>>1), src=(r&1)*800+h; r>=128: h=64j+(r-128), src=1600+h.
// zf-only (z=2): Wzf[1664][Kpad]; row n: h=n>>1, src=(n&1)*800+h. ----
__global__ __launch_bounds__(256) void transpose_cast_w(
    const float* __restrict__ W0, const float* __restrict__ W1,
    const float* __restrict__ W2, bf16_t* __restrict__ M0,
    bf16_t* __restrict__ M1, bf16_t* __restrict__ Z2) {
  const int z = blockIdx.z;
  const float* W = z == 0 ? W0 : (z == 1 ? W1 : W2);
  bf16_t* Wt = z == 0 ? M0 : (z == 1 ? M1 : Z2);
  const int K = z == 0 ? 300 : 800;
  const int Kpad = z == 0 ? 320 : 832;
  const int Npad = (z < 2) ? 2496 : 1664;
  const int i = blockIdx.x, j = blockIdx.y;
  if (i * 32 >= Npad || j * 32 >= Kpad) return;
  __shared__ float tile[32][33];
  const int tx = threadIdx.x & 31, ty = threadIdx.x >> 5;
#pragma unroll
  for (int r = 0; r < 32; r += 8) {
    const int k = j * 32 + ty + r;
    const int n = i * 32 + tx;
    int h, src;
    if (z < 2) {
      const int jt = n / 192, rr = n - jt * 192;
      if (rr < 128) {
        h = jt * 64 + (rr >> 1);
        src = (rr & 1) * 800 + h;
      } else {
        h = jt * 64 + (rr - 128);
        src = 1600 + h;
      }
    } else {
      h = n >> 1;
      src = (n & 1) * 800 + h;
    }
    const bool valid = (k < K) && (h < 800);
    tile[ty + r][tx] = valid ? W[(size_t)k * 2400 + src] : 0.0f;
  }
  __syncthreads();
#pragma unroll
  for (int r = 0; r < 32; r += 8) {
    const int n = i * 32 + ty + r, k = j * 32 + tx;
    if (n < Npad && k < Kpad)
      Wt[(size_t)n * Kpad + k] = (bf16_t)tile[tx][ty + r];
  }
}

// ---- async 16B global->LDS (wave-uniform base + lane*16 layout) ----
__device__ __forceinline__ void stage16(const bf16_t* gp, bf16_t* lp) {
  __builtin_amdgcn_global_load_lds((__attribute__((address_space(1))) void*)gp,
                                   (__attribute__((address_space(3))) void*)lp,
                                   16, 0, 0);
}

// GEMM core: 128 x (32*NTF) tile of A@Wt^T into Et[128][ETS] (bf16).
// 2x2 waves; each wave = 64 rows x (16*NTF) cols. XOR-swizzled staging,
// conflict-free ds_read_b128 fragment reads. B rows staged in NTF passes.
template <int NTF, int ETS>
__device__ __forceinline__ void gemm_tile_to_lds(
    const bf16_t* __restrict__ A, const bf16_t* __restrict__ Bt,
    bf16_t* __restrict__ S, int K, int mBase, int nBase) {
  bf16_t* As = S;
  bf16_t* Bs = S + 8192;
  const int tid = threadIdx.x;
  const int wave = tid >> 6, lane = tid & 63;
  const int wm = wave >> 1, wn = wave & 1;
  const int srow = tid >> 3;
  const int scolSw = ((tid & 7) ^ (srow & 7)) * 8;
  const size_t aBase = (size_t)(mBase + srow) * K + scolSw;
  const size_t bBase = (size_t)(nBase + srow) * K + scolSw;
  const int ldsOff = tid * 8;

  f32x4 acc[4][NTF];
#pragma unroll
  for (int mt = 0; mt < 4; ++mt)
#pragma unroll
    for (int nt = 0; nt < NTF; ++nt) {
      f32x4 zz = {0.0f, 0.0f, 0.0f, 0.0f};
      acc[mt][nt] = zz;
    }

  const int fr = lane & 15, fq = lane >> 4;
  const int x0 = fr & 7;
  const int ckEl0 = (fq ^ x0) * 8;
  const int ckEl1 = ((4 + fq) ^ x0) * 8;

  for (int k0 = 0; k0 < K; k0 += 64) {
#pragma unroll
    for (int p = 0; p < 4; ++p)
      stage16(A + aBase + (size_t)(32 * p) * K + k0, &As[ldsOff + p * 2048]);
#pragma unroll
    for (int p = 0; p < NTF; ++p)
      stage16(Bt + bBase + (size_t)(32 * p) * K + k0, &Bs[ldsOff + p * 2048]);
    __syncthreads();
#pragma unroll
    for (int kh = 0; kh < 2; ++kh) {
      const int ck = kh ? ckEl1 : ckEl0;
      bf16x8 af[4], bfv[NTF];
#pragma unroll
      for (int mt = 0; mt < 4; ++mt)
        af[mt] = *(const bf16x8*)&As[(wm * 64 + mt * 16 + fr) * 64 + ck];
#pragma unroll
      for (int nt = 0; nt < NTF; ++nt)
        bfv[nt] = *(const bf16x8*)&Bs[(wn * (16 * NTF) + nt * 16 + fr) * 64 + ck];
#pragma unroll
      for (int mt = 0; mt < 4; ++mt)
#pragma unroll
        for (int nt = 0; nt < NTF; ++nt)
          acc[mt][nt] = __builtin_amdgcn_mfma_f32_16x16x32_bf16(
              af[mt], bfv[nt], acc[mt][nt], 0, 0, 0);
    }
    __syncthreads();
  }
  // C/D layout col=lane&15, row=(lane>>4)*4+r -> Et[row][col], stride ETS.
  bf16_t* Et = S;
#pragma unroll
  for (int mt = 0; mt < 4; ++mt)
#pragma unroll
    for (int nt = 0; nt < NTF; ++nt)
#pragma unroll
      for (int r = 0; r < 4; ++r)
        Et[(wm * 64 + mt * 16 + fq * 4 + r) * ETS + wn * (16 * NTF) + nt * 16 +
           fr] = (bf16_t)acc[mt][nt][r];
  __syncthreads();
}

// ---- L0/L1: zfo-GEMM (192 cols/block) + fused scan + h epilogue ----
// Grid (13, 64). m-tile = batch b; block covers h in [64j, 64j+64).
// Et[t][2hl+g] = raw z',f'; Et[t][128+hl] = raw o'.
__global__ __launch_bounds__(256, 3) void gemm_scan_h(
    const bf16_t* __restrict__ A, const bf16_t* __restrict__ Wm,
    const float* __restrict__ bias, bf16_t* __restrict__ Hout,
    float* __restrict__ carry, float* __restrict__ outC, int K, int outOff,
    int first, int last) {
  __shared__ __align__(16) bf16_t S[25088];  // staging 20480; Et 128*196
  __shared__ float SA[4][64], SB[4][64], SC[4][64];
  const int nT = gridDim.x;  // 13
  const int L = blockIdx.y * nT + blockIdx.x;
  const int xcd = L & 7, j = L >> 3;
  const int b = xcd * 8 + j / nT;
  const int ntile = j % nT;
  gemm_tile_to_lds<6, 196>(A, Wm, S, K, b * 128, ntile * 192);

  const uint32_t* Ep = (const uint32_t*)S;  // dword idx t*98+hl = (z,f)
  const int tid = threadIdx.x;
  const int hl = tid & 63, s = tid >> 6;
  const int h = ntile * 64 + hl;
  const bool hOK = (h < HID);
  const int hb = hOK ? h : 0;
  const float bz = bias[hb], bf = bias[hb + 800], bo = bias[hb + 1600];

  // phase 1: activate once, cache affine coeffs, compose segment map
  float av[32], bv[32];
  float Aa = 1.0f, Bb = 0.0f;
#pragma unroll
  for (int q = 0; q < 32; ++q) {
    const int t = s * 32 + q;
    const uint32_t v = Ep[t * 98 + hl];
    const float zv = fast_tanh(b2f(v & 0xffffu) + bz);
    const float fv = fast_sigmoid(b2f(v >> 16) + bf);
    av[q] = 1.0f - fv;
    bv[q] = fv * zv;
    Aa *= av[q];
    Bb = fmaf(av[q], Bb, bv[q]);
  }
  SA[s][hl] = Aa;
  SB[s][hl] = Bb;
  __syncthreads();
  // phase 2: serial combine over 4 segments, one thread per chain
  if (tid < 64) {
    const int h2 = ntile * 64 + tid;
    const bool ok2 = (h2 < HID);
    float c = (first || !ok2) ? 0.0f : carry[b * HID + h2];
#pragma unroll
    for (int ss = 0; ss < 4; ++ss) {
      SC[ss][tid] = c;
      c = fmaf(SA[ss][tid], c, SB[ss][tid]);
    }
    if (ok2) {
      carry[b * HID + h2] = c;
      if (last) outC[b * 2400 + outOff + h2] = c;
    }
  }
  __syncthreads();
  // phase 3: fma rescan from registers; h = sigmoid(o'+bo) * c (fp32 c)
  float c = SC[s][hl];
#pragma unroll
  for (int q = 0; q < 32; ++q) {
    const int t = s * 32 + q;
    c = fmaf(av[q], c, bv[q]);  // a*c + b == f*z + (1-f)*c
    const float o = fast_sigmoid((float)S[t * 196 + 128 + hl] + bo);
    Hout[(size_t)(b * 128 + t) * LDH + h] =
        hOK ? (bf16_t)(o * c) : (bf16_t)0.0f;  // zero K-pad cols [800,832)
  }
}

// ---- L2: zf-only GEMM (128 cols/block) + scan; carry/out only ----
__global__ __launch_bounds__(256, 3) void gemm_scan_c(
    const bf16_t* __restrict__ A, const bf16_t* __restrict__ Wzf,
    const float* __restrict__ bias, float* __restrict__ carry,
    float* __restrict__ outC, int K, int outOff, int first, int last) {
  __shared__ __align__(16) bf16_t S[17920];
  __shared__ float SA[4][64], SB[4][64];
  const int nT = gridDim.x;  // 13
  const int L = blockIdx.y * nT + blockIdx.x;
  const int xcd = L & 7, j = L >> 3;
  const int b = xcd * 8 + j / nT;
  const int ntile = j % nT;
  gemm_tile_to_lds<4, 140>(A, Wzf, S, K, b * 128, ntile * 128);

  const uint32_t* Ep = (const uint32_t*)S;  // dword idx t*70+hl = (z,f)
  const int tid = threadIdx.x;
  const int hl = tid & 63, s = tid >> 6;
  const int h = ntile * 64 + hl;
  const bool hOK = (h < HID);
  const int hb = hOK ? h : 0;
  const float bz = bias[hb], bf = bias[hb + 800];

  float Aa = 1.0f, Bb = 0.0f;
#pragma unroll
  for (int q = 0; q < 32; ++q) {
    const int t = s * 32 + q;
    const uint32_t v = Ep[t * 70 + hl];
    const float zv = fast_tanh(b2f(v & 0xffffu) + bz);
    const float fv = fast_sigmoid(b2f(v >> 16) + bf);
    const float a = 1.0f - fv;
    Aa *= a;
    Bb = fmaf(a, Bb, fv * zv);
  }
  SA[s][hl] = Aa;
  SB[s][hl] = Bb;
  __syncthreads();
  if (tid < 64) {
    const int h2 = ntile * 64 + tid;
    const bool ok2 = (h2 < HID);
    float c = (first || !ok2) ? 0.0f : carry[b * HID + h2];
#pragma unroll
    for (int ss = 0; ss < 4; ++ss) c = fmaf(SA[ss][tid], c, SB[ss][tid]);
    if (ok2) {
      carry[b * HID + h2] = c;
      if (last) outC[b * 2400 + outOff + h2] = c;
    }
  }
}

extern "C" void kernel_launch(void* const* d_in, const int* in_sizes, int n_in,
                              void* d_out, int out_size, void* d_ws, size_t ws_size,
                              hipStream_t stream) {
  const float* sent = (const float*)d_in[0];
  // d_in[1] = lengths: unused by the reference
  const float* W0 = (const float*)d_in[2];
  const float* b0 = (const float*)d_in[3];
  const float* W1 = (const float*)d_in[4];
  const float* b1 = (const float*)d_in[5];
  const float* W2 = (const float*)d_in[6];
  const float* b2 = (const float*)d_in[7];
  float* out = (float*)d_out;

  char* ws = (char*)d_ws;
  size_t off = 0;
  auto alloc = [&](size_t bytes) {
    void* p = ws + off;
    off += (bytes + 255) & ~(size_t)255;
    return p;
  };
  bf16_t* Wm0 = (bf16_t*)alloc((size_t)2496 * 320 * 2);   // 1.6 MB
  bf16_t* Wm1 = (bf16_t*)alloc((size_t)2496 * 832 * 2);   // 4.2 MB
  bf16_t* Wzf2 = (bf16_t*)alloc((size_t)1664 * 832 * 2);  // 2.8 MB
  bf16_t* A0 = (bf16_t*)alloc((size_t)32768 * 320 * 2);   // 21.0 MB
  bf16_t* H0c = (bf16_t*)alloc((size_t)MC * LDH * 2);     // 13.6 MB
  bf16_t* H1c = (bf16_t*)alloc((size_t)MC * LDH * 2);     // 13.6 MB
  float* car0 = (float*)alloc((size_t)BATCH * HID * 4);   // 205 KB
  float* car1 = (float*)alloc((size_t)BATCH * HID * 4);
  float* car2 = (float*)alloc((size_t)BATCH * HID * 4);
  if (off > ws_size) return;  // ws too small: fail verification, don't fault

  cast_reorder_a0<<<(32768 * 320 + 255) / 256, 256, 0, stream>>>(sent, A0);
  transpose_cast_w<<<dim3(78, 26, 3), 256, 0, stream>>>(W0, W1, W2, Wm0, Wm1,
                                                        Wzf2);

  for (int c = 0; c < NCHUNK; ++c) {
    const int first = (c == 0), last = (c == NCHUNK - 1);
    const bf16_t* A0c = A0 + (size_t)c * MC * 320;
    // layer 0 (K=320): zfo GEMM + scan + h -> H0c
    gemm_scan_h<<<dim3(13, 64), 256, 0, stream>>>(A0c, Wm0, b0, H0c, car0, out,
                                                  320, 0, first, last);
    // layer 1 (K=832): zfo GEMM + scan + h -> H1c
    gemm_scan_h<<<dim3(13, 64), 256, 0, stream>>>(H0c, Wm1, b1, H1c, car1, out,
                                                  832, 800, first, last);
    // layer 2 (K=832): zf-only GEMM + scan -> carry/out
    gemm_scan_c<<<dim3(13, 64), 256, 0, stream>>>(H1c, Wzf2, b2, car2, out,
                                                  832, 1600, first, last);
  }
}